// Round 1
// baseline (50.279 us; speedup 1.0000x reference)
//
#include <hip/hip_runtime.h>

#define Bc 2048
#define Tc 50
#define Lc 30
#define Nc 1000
#define NFc 2
#define EMBc 32
#define SEMBc 12

__global__ __launch_bounds__(256) void gnnsage_kernel(
    const int*   __restrict__ stops,      // B,T
    const float* __restrict__ x,          // B,L,N
    const float* __restrict__ x_dist,     // N
    const float* __restrict__ x_features, // B,NF
    const int*   __restrict__ x_week,     // B
    const int*   __restrict__ x_mask,     // B,N
    const float* __restrict__ emb_week,   // NWD,EMB
    const float* __restrict__ emb_stop,   // N,SEMB
    const float* __restrict__ W_l,        // L
    const float* __restrict__ b_l,        // 1
    const float* __restrict__ W_r,        // L
    const float* __restrict__ fc2_W,      // 48
    const float* __restrict__ fc2_b,      // 1
    float*       __restrict__ out)        // B,N
{
    __shared__ float sWl[Lc], sWr[Lc];
    __shared__ float wl[Nc];       // dot(x[b,:,n], W_l)
    __shared__ float lg[Nc];       // dot(x[b,:,n], W_r) -> logits
    __shared__ float seg_sum[Nc];
    __shared__ float seg_cnt[Nc];
    __shared__ float s_cb;
    __shared__ float s_red[4];
    __shared__ float s_bcast;

    const int b   = blockIdx.x;
    const int tid = threadIdx.x;
    const float* xb = x + (size_t)b * (Lc * Nc);
    const int*   st = stops + b * Tc;

    // ---- phase 0: init ----
    if (tid < Lc) { sWl[tid] = W_l[tid]; sWr[tid] = W_r[tid]; }
    for (int n = tid; n < Nc; n += 256) { seg_sum[n] = 0.f; seg_cnt[n] = 0.f; }
    if (tid == 0) {
        float cb = fc2_b[0];
        const float* ew = emb_week + x_week[b] * EMBc;
        #pragma unroll
        for (int i = 0; i < EMBc; ++i) cb += ew[i] * fc2_W[i];
        cb += x_features[b * NFc + 0] * fc2_W[EMBc + 0];
        cb += x_features[b * NFc + 1] * fc2_W[EMBc + 1];
        s_cb = cb;
    }
    __syncthreads();

    // ---- phase 1a: per-stop embedding contribution to C_b (all T=50 stops) ----
    if (tid < Tc) {
        const float* es = emb_stop + st[tid] * SEMBc;
        float p = 0.f;
        #pragma unroll
        for (int i = 0; i < SEMBc; ++i) p += es[i] * fc2_W[EMBc + NFc + i];
        atomicAdd(&s_cb, p);
    }

    // ---- phase 1b: single streaming pass over x[b] (float4, coalesced) ----
    if (tid < Nc / 4) {
        const int n0 = tid * 4;
        float4 sl = make_float4(0.f, 0.f, 0.f, 0.f);
        float4 sr = make_float4(0.f, 0.f, 0.f, 0.f);
        #pragma unroll
        for (int l = 0; l < Lc; ++l) {
            float4 v = *reinterpret_cast<const float4*>(xb + l * Nc + n0);
            float a = sWl[l], r = sWr[l];
            sl.x += v.x * a; sl.y += v.y * a; sl.z += v.z * a; sl.w += v.w * a;
            sr.x += v.x * r; sr.y += v.y * r; sr.z += v.z * r; sr.w += v.w * r;
        }
        *reinterpret_cast<float4*>(&wl[n0]) = sl;
        *reinterpret_cast<float4*>(&lg[n0]) = sr;
    }
    __syncthreads();

    // ---- phase 2: edge scatter into segments (mean aggr, commuted with W_l dot) ----
    if (tid < Tc - 1) {
        int s = st[tid], d = st[tid + 1];
        atomicAdd(&seg_sum[d], wl[s]);
        atomicAdd(&seg_cnt[d], 1.0f);
    }
    __syncthreads();

    // ---- phase 3: finalize logits ----
    const float cb  = s_cb;
    const float w46 = fc2_W[EMBc + NFc + SEMBc];       // weight for 'out' feature
    const float w47 = fc2_W[EMBc + NFc + SEMBc + 1];   // weight for x_dist feature
    const float bl  = b_l[0];
    float lmax = -3.0e38f;
    for (int n = tid; n < Nc; n += 256) {
        float c = seg_cnt[n];
        float a = (c > 0.f) ? seg_sum[n] / c : 0.f;
        float v = cb + w46 * (a + bl + lg[n]) + w47 * x_dist[n];
        lg[n] = v;
        lmax = fmaxf(lmax, v);
    }

    // ---- phase 4: block log-sum-exp ----
    #pragma unroll
    for (int off = 32; off > 0; off >>= 1) lmax = fmaxf(lmax, __shfl_xor(lmax, off));
    const int wid = tid >> 6;
    if ((tid & 63) == 0) s_red[wid] = lmax;
    __syncthreads();
    if (tid == 0)
        s_bcast = fmaxf(fmaxf(s_red[0], s_red[1]), fmaxf(s_red[2], s_red[3]));
    __syncthreads();
    const float mx = s_bcast;

    float lsum = 0.f;
    for (int n = tid; n < Nc; n += 256) lsum += expf(lg[n] - mx);
    #pragma unroll
    for (int off = 32; off > 0; off >>= 1) lsum += __shfl_xor(lsum, off);
    if ((tid & 63) == 0) s_red[wid] = lsum;
    __syncthreads();
    if (tid == 0) s_bcast = logf(s_red[0] + s_red[1] + s_red[2] + s_red[3]);
    __syncthreads();
    const float lse = mx + s_bcast;

    // ---- phase 5: masked write ----
    const int* mk = x_mask + (size_t)b * Nc;
    float* ob = out + (size_t)b * Nc;
    for (int n = tid; n < Nc; n += 256) {
        ob[n] = mk[n] ? -100000000.0f : (lg[n] - lse);
    }
}

extern "C" void kernel_launch(void* const* d_in, const int* in_sizes, int n_in,
                              void* d_out, int out_size, void* d_ws, size_t ws_size,
                              hipStream_t stream) {
    const int*   stops      = (const int*)  d_in[0];
    const float* x          = (const float*)d_in[1];
    const float* x_dist     = (const float*)d_in[2];
    const float* x_features = (const float*)d_in[3];
    const int*   x_week     = (const int*)  d_in[4];
    const int*   x_mask     = (const int*)  d_in[5];
    const float* emb_week   = (const float*)d_in[6];
    const float* emb_stop   = (const float*)d_in[7];
    const float* W_l        = (const float*)d_in[8];
    const float* b_l        = (const float*)d_in[9];
    const float* W_r        = (const float*)d_in[10];
    const float* fc2_W      = (const float*)d_in[11];
    const float* fc2_b      = (const float*)d_in[12];
    float* out = (float*)d_out;

    gnnsage_kernel<<<Bc, 256, 0, stream>>>(stops, x, x_dist, x_features, x_week,
                                           x_mask, emb_week, emb_stop, W_l, b_l,
                                           W_r, fc2_W, fc2_b, out);
}

// Round 2
// 46.766 us; speedup vs baseline: 1.0751x; 1.0751x over previous
//
#include <hip/hip_runtime.h>

#define Bc 2048
#define Tc 50
#define Lc 30
#define Nc 1000
#define NFc 2
#define EMBc 32
#define SEMBc 12

typedef float f4 __attribute__((ext_vector_type(4)));
typedef int   i4 __attribute__((ext_vector_type(4)));

__global__ __launch_bounds__(256) void gnnsage_kernel(
    const int*   __restrict__ stops,      // B,T
    const float* __restrict__ x,          // B,L,N
    const float* __restrict__ x_dist,     // N
    const float* __restrict__ x_features, // B,NF
    const int*   __restrict__ x_week,     // B
    const int*   __restrict__ x_mask,     // B,N
    const float* __restrict__ emb_week,   // NWD,EMB
    const float* __restrict__ emb_stop,   // N,SEMB
    const float* __restrict__ W_l,        // L
    const float* __restrict__ b_l,        // 1
    const float* __restrict__ W_r,        // L
    const float* __restrict__ fc2_W,      // 48
    const float* __restrict__ fc2_b,      // 1
    float*       __restrict__ out)        // B,N
{
    __shared__ float sWl[Lc], sWr[Lc];
    __shared__ float wl[Nc];       // dot(x[b,:,n], W_l)  (needed for edge gather)
    __shared__ float seg_sum[Nc];
    __shared__ float seg_cnt[Nc];
    __shared__ float s_cb;
    __shared__ float s_red[4];
    __shared__ float s_bcast;

    const int b   = blockIdx.x;
    const int tid = threadIdx.x;
    const float* xb = x + (size_t)b * (Lc * Nc);

    // ---- phase 0: init + prefetch (all overlapped with stream issue) ----
    if (tid < Lc) { sWl[tid] = W_l[tid]; sWr[tid] = W_r[tid]; }
    for (int n = tid; n < Nc; n += 256) { seg_sum[n] = 0.f; seg_cnt[n] = 0.f; }

    i4 mk = (i4)0;
    f4 d4 = (f4)0.f;
    if (tid < Nc / 4) {
        mk = ((const i4*)(x_mask + (size_t)b * Nc))[tid];
        d4 = ((const f4*)x_dist)[tid];
    }

    // per-stop embedding contribution (wave 0, register + shuffle reduce)
    float p = 0.f;
    int st_t = 0;
    if (tid < Tc) {
        st_t = stops[b * Tc + tid];
        const float* es = emb_stop + st_t * SEMBc;
        #pragma unroll
        for (int i = 0; i < SEMBc; ++i) p += es[i] * fc2_W[EMBc + NFc + i];
    }
    if (tid < 64) {
        #pragma unroll
        for (int off = 32; off > 0; off >>= 1) p += __shfl_xor(p, off);
    }
    if (tid == 0) {
        float cb = fc2_b[0] + p;
        const float* ew = emb_week + x_week[b] * EMBc;
        #pragma unroll
        for (int i = 0; i < EMBc; ++i) cb += ew[i] * fc2_W[i];
        cb += x_features[b * NFc + 0] * fc2_W[EMBc + 0];
        cb += x_features[b * NFc + 1] * fc2_W[EMBc + 1];
        s_cb = cb;
    }
    __syncthreads();

    // ---- phase 1: single streaming pass over x[b] (nontemporal float4) ----
    f4 sr = (f4)0.f;   // x . W_r for this thread's 4 columns (stays in regs)
    if (tid < Nc / 4) {
        f4 sl = (f4)0.f;
        #pragma unroll
        for (int l = 0; l < Lc; ++l) {
            f4 v = __builtin_nontemporal_load((const f4*)(xb + l * Nc) + tid);
            sl += v * sWl[l];
            sr += v * sWr[l];
        }
        *((f4*)&wl[tid * 4]) = sl;
    }
    __syncthreads();

    // ---- phase 2: edge scatter (mean aggr commuted with W_l dot), wave 0 ----
    if (tid < 64) {
        int d = __shfl(st_t, tid + 1);
        if (tid < Tc - 1) {
            atomicAdd(&seg_sum[d], wl[st_t]);
            atomicAdd(&seg_cnt[d], 1.0f);
        }
    }
    __syncthreads();

    // ---- phase 3: finalize logits (registers, vectorized) ----
    const float cb  = s_cb;
    const float w46 = fc2_W[EMBc + NFc + SEMBc];
    const float w47 = fc2_W[EMBc + NFc + SEMBc + 1];
    const float bl  = b_l[0];
    float lmax = -3.0e38f;
    f4 v4 = (f4)0.f;
    if (tid < Nc / 4) {
        const int n0 = tid * 4;
        f4 ss = *((const f4*)&seg_sum[n0]);
        f4 sc = *((const f4*)&seg_cnt[n0]);
        f4 a;
        a.x = sc.x > 0.f ? ss.x / sc.x : 0.f;
        a.y = sc.y > 0.f ? ss.y / sc.y : 0.f;
        a.z = sc.z > 0.f ? ss.z / sc.z : 0.f;
        a.w = sc.w > 0.f ? ss.w / sc.w : 0.f;
        v4 = cb + w46 * (a + bl + sr) + w47 * d4;
        lmax = fmaxf(fmaxf(v4.x, v4.y), fmaxf(v4.z, v4.w));
    }

    // ---- phase 4: block log-sum-exp ----
    #pragma unroll
    for (int off = 32; off > 0; off >>= 1) lmax = fmaxf(lmax, __shfl_xor(lmax, off));
    const int wid = tid >> 6;
    if ((tid & 63) == 0) s_red[wid] = lmax;
    __syncthreads();
    if (tid == 0)
        s_bcast = fmaxf(fmaxf(s_red[0], s_red[1]), fmaxf(s_red[2], s_red[3]));
    __syncthreads();
    const float mx = s_bcast;

    float lsum = 0.f;
    if (tid < Nc / 4)
        lsum = __expf(v4.x - mx) + __expf(v4.y - mx) + __expf(v4.z - mx) + __expf(v4.w - mx);
    #pragma unroll
    for (int off = 32; off > 0; off >>= 1) lsum += __shfl_xor(lsum, off);
    if ((tid & 63) == 0) s_red[wid] = lsum;
    __syncthreads();
    if (tid == 0) s_bcast = logf(s_red[0] + s_red[1] + s_red[2] + s_red[3]);
    __syncthreads();
    const float lse = mx + s_bcast;

    // ---- phase 5: masked write (registers, nontemporal float4) ----
    if (tid < Nc / 4) {
        f4 o;
        o.x = mk.x ? -100000000.0f : (v4.x - lse);
        o.y = mk.y ? -100000000.0f : (v4.y - lse);
        o.z = mk.z ? -100000000.0f : (v4.z - lse);
        o.w = mk.w ? -100000000.0f : (v4.w - lse);
        __builtin_nontemporal_store(o, (f4*)(out + (size_t)b * Nc) + tid);
    }
}

extern "C" void kernel_launch(void* const* d_in, const int* in_sizes, int n_in,
                              void* d_out, int out_size, void* d_ws, size_t ws_size,
                              hipStream_t stream) {
    const int*   stops      = (const int*)  d_in[0];
    const float* x          = (const float*)d_in[1];
    const float* x_dist     = (const float*)d_in[2];
    const float* x_features = (const float*)d_in[3];
    const int*   x_week     = (const int*)  d_in[4];
    const int*   x_mask     = (const int*)  d_in[5];
    const float* emb_week   = (const float*)d_in[6];
    const float* emb_stop   = (const float*)d_in[7];
    const float* W_l        = (const float*)d_in[8];
    const float* b_l        = (const float*)d_in[9];
    const float* W_r        = (const float*)d_in[10];
    const float* fc2_W      = (const float*)d_in[11];
    const float* fc2_b      = (const float*)d_in[12];
    float* out = (float*)d_out;

    gnnsage_kernel<<<Bc, 256, 0, stream>>>(stops, x, x_dist, x_features, x_week,
                                           x_mask, emb_week, emb_stop, W_l, b_l,
                                           W_r, fc2_W, fc2_b, out);
}

// Round 3
// 45.333 us; speedup vs baseline: 1.1091x; 1.0316x over previous
//
#include <hip/hip_runtime.h>

#define Bc 2048
#define Tc 50
#define Lc 30
#define Nc 1000
#define NFc 2
#define EMBc 32
#define SEMBc 12

typedef float f4 __attribute__((ext_vector_type(4)));
typedef int   i4 __attribute__((ext_vector_type(4)));

__global__ __launch_bounds__(256) void gnnsage_kernel(
    const int*   __restrict__ stops,      // B,T
    const float* __restrict__ x,          // B,L,N
    const float* __restrict__ x_dist,     // N
    const float* __restrict__ x_features, // B,NF
    const int*   __restrict__ x_week,     // B
    const int*   __restrict__ x_mask,     // B,N
    const float* __restrict__ emb_week,   // NWD,EMB
    const float* __restrict__ emb_stop,   // N,SEMB
    const float* __restrict__ W_l,        // L
    const float* __restrict__ b_l,        // 1
    const float* __restrict__ W_r,        // L
    const float* __restrict__ fc2_W,      // 48
    const float* __restrict__ fc2_b,      // 1
    float*       __restrict__ out)        // B,N
{
    __shared__ float wl[Nc];       // dot(x[b,:,n], W_l)  (for edge gather)
    __shared__ float seg_sum[Nc];
    __shared__ float seg_cnt[Nc];
    __shared__ float s_cbp[2];
    __shared__ float s_redM[4];
    __shared__ float s_redS[4];

    const int b   = blockIdx.x;
    const int tid = threadIdx.x;
    const float* xb = x + (size_t)b * (Lc * Nc);

    // ---- init (no barrier: only consumed after barrier B) ----
    for (int n = tid; n < Nc; n += 256) { seg_sum[n] = 0.f; seg_cnt[n] = 0.f; }

    // ---- early independent loads ----
    i4 mk = (i4)0;
    f4 d4 = (f4)0.f;
    if (tid < Nc / 4) {
        mk = __builtin_nontemporal_load(((const i4*)(x_mask + (size_t)b * Nc)) + tid);
        d4 = ((const f4*)x_dist)[tid];
    }
    int st_t = 0;
    if (tid < Tc) st_t = stops[b * Tc + tid];

    // ---- phase 1: single streaming pass over x[b] (nontemporal float4) ----
    // W_l[l]/W_r[l] are wave-uniform -> scalar loads, no LDS staging needed.
    f4 sr = (f4)0.f;   // x . W_r for this thread's 4 columns (stays in regs)
    if (tid < Nc / 4) {
        f4 sl = (f4)0.f;
        #pragma unroll
        for (int l = 0; l < Lc; ++l) {
            f4 v = __builtin_nontemporal_load((const f4*)(xb + l * Nc) + tid);
            sl += v * W_l[l];
            sr += v * W_r[l];
        }
        *((f4*)&wl[tid * 4]) = sl;
    }

    // ---- C_b partials (latency hidden under streaming of other waves/blocks) ----
    if (tid < 64) {
        // wave 0: per-stop embedding contribution
        float p = 0.f;
        if (tid < Tc) {
            const float* es = emb_stop + st_t * SEMBc;
            #pragma unroll
            for (int i = 0; i < SEMBc; ++i) p += es[i] * fc2_W[EMBc + NFc + i];
        }
        #pragma unroll
        for (int off = 32; off > 0; off >>= 1) p += __shfl_xor(p, off);
        if (tid == 0) s_cbp[0] = p;
    } else if (tid < 96) {
        // wave 1 lanes 0..31: week embedding dot + features + bias
        const int i = tid - 64;
        const int wk = x_week[b];
        float q = emb_week[wk * EMBc + i] * fc2_W[i];
        #pragma unroll
        for (int off = 16; off > 0; off >>= 1) q += __shfl_xor(q, off);
        if (tid == 64) {
            q += fc2_b[0];
            q += x_features[b * NFc + 0] * fc2_W[EMBc + 0];
            q += x_features[b * NFc + 1] * fc2_W[EMBc + 1];
            s_cbp[1] = q;
        }
    }
    __syncthreads();   // B: wl + seg-init + s_cbp ready

    // ---- phase 2: edge scatter (mean aggr commuted with W_l dot), wave 0 ----
    if (tid < 64) {
        int d = __shfl(st_t, tid + 1);
        if (tid < Tc - 1) {
            atomicAdd(&seg_sum[d], wl[st_t]);
            atomicAdd(&seg_cnt[d], 1.0f);
        }
    }
    __syncthreads();   // C: seg arrays final

    // ---- phase 3: finalize logits (registers, vectorized) ----
    const float cb  = s_cbp[0] + s_cbp[1];
    const float w46 = fc2_W[EMBc + NFc + SEMBc];
    const float w47 = fc2_W[EMBc + NFc + SEMBc + 1];
    const float bl  = b_l[0];
    float lmax = -3.0e38f;
    f4 v4 = (f4)0.f;
    if (tid < Nc / 4) {
        const int n0 = tid * 4;
        f4 ss = *((const f4*)&seg_sum[n0]);
        f4 sc = *((const f4*)&seg_cnt[n0]);
        f4 a;
        a.x = sc.x > 0.f ? ss.x / sc.x : 0.f;
        a.y = sc.y > 0.f ? ss.y / sc.y : 0.f;
        a.z = sc.z > 0.f ? ss.z / sc.z : 0.f;
        a.w = sc.w > 0.f ? ss.w / sc.w : 0.f;
        v4 = cb + w46 * (a + bl + sr) + w47 * d4;
        lmax = fmaxf(fmaxf(v4.x, v4.y), fmaxf(v4.z, v4.w));
    }

    // ---- phase 4: block log-sum-exp (2 barriers) ----
    #pragma unroll
    for (int off = 32; off > 0; off >>= 1) lmax = fmaxf(lmax, __shfl_xor(lmax, off));
    const int wid = tid >> 6;
    if ((tid & 63) == 0) s_redM[wid] = lmax;
    __syncthreads();   // M
    const float mx = fmaxf(fmaxf(s_redM[0], s_redM[1]), fmaxf(s_redM[2], s_redM[3]));

    float lsum = 0.f;
    if (tid < Nc / 4)
        lsum = __expf(v4.x - mx) + __expf(v4.y - mx) + __expf(v4.z - mx) + __expf(v4.w - mx);
    #pragma unroll
    for (int off = 32; off > 0; off >>= 1) lsum += __shfl_xor(lsum, off);
    if ((tid & 63) == 0) s_redS[wid] = lsum;
    __syncthreads();   // S
    const float lse = mx + logf(s_redS[0] + s_redS[1] + s_redS[2] + s_redS[3]);

    // ---- phase 5: masked write (registers, nontemporal float4) ----
    if (tid < Nc / 4) {
        f4 o;
        o.x = mk.x ? -100000000.0f : (v4.x - lse);
        o.y = mk.y ? -100000000.0f : (v4.y - lse);
        o.z = mk.z ? -100000000.0f : (v4.z - lse);
        o.w = mk.w ? -100000000.0f : (v4.w - lse);
        __builtin_nontemporal_store(o, (f4*)(out + (size_t)b * Nc) + tid);
    }
}

extern "C" void kernel_launch(void* const* d_in, const int* in_sizes, int n_in,
                              void* d_out, int out_size, void* d_ws, size_t ws_size,
                              hipStream_t stream) {
    const int*   stops      = (const int*)  d_in[0];
    const float* x          = (const float*)d_in[1];
    const float* x_dist     = (const float*)d_in[2];
    const float* x_features = (const float*)d_in[3];
    const int*   x_week     = (const int*)  d_in[4];
    const int*   x_mask     = (const int*)  d_in[5];
    const float* emb_week   = (const float*)d_in[6];
    const float* emb_stop   = (const float*)d_in[7];
    const float* W_l        = (const float*)d_in[8];
    const float* b_l        = (const float*)d_in[9];
    const float* W_r        = (const float*)d_in[10];
    const float* fc2_W      = (const float*)d_in[11];
    const float* fc2_b      = (const float*)d_in[12];
    float* out = (float*)d_out;

    gnnsage_kernel<<<Bc, 256, 0, stream>>>(stops, x, x_dist, x_features, x_week,
                                           x_mask, emb_week, emb_stop, W_l, b_l,
                                           W_r, fc2_W, fc2_b, out);
}